// Round 14
// baseline (236.520 us; speedup 1.0000x reference)
//
#include <hip/hip_runtime.h>
#include <hip/hip_fp16.h>
#include <math.h>

#define BIG_NEG  (-1.0e6f)
#define NN   100
#define MD   128
#define KD   256
#define G4   512
#define NB   2    // batch elements per block (68 KB LDS -> 2 blocks/CU)
#define MP2  68   // __half2 stride per mem row (272 B, 16B-aligned)
#define XPAD 288  // xcath row stride in halves

// ws layout:
//   halves [0, 32768)       : WembF embed B-frags [kg:32][m:128][j:8]
//   halves [32768, 163840)  : WGF gates B-frags [kc:32][g:512][j:8], k = kc*8+j
//   floats [81920, 82432)   : biasc = b_ih + b_hh
#define WS_WGF_H  32768
#define WS_BIAS_F 81920

typedef _Float16 f16x2 __attribute__((ext_vector_type(2)));
typedef _Float16 f16x8 __attribute__((ext_vector_type(8)));
typedef float    f32x4 __attribute__((ext_vector_type(4)));

#if __has_builtin(__builtin_amdgcn_rcpf)
#define RCPF(x) __builtin_amdgcn_rcpf(x)
#else
#define RCPF(x) (1.0f / (x))
#endif

#define PKRTZ(a, b) __builtin_bit_cast(unsigned, __builtin_amdgcn_cvt_pkrtz((a), (b)))

__device__ __forceinline__ float sigm(float x) {
    return RCPF(1.0f + __expf(-x));
}
__device__ __forceinline__ float tanh_f(float x) {
    float xc = fminf(fmaxf(x, -15.0f), 15.0f);
    float e  = __expf(2.0f * xc);
    return (e - 1.0f) * RCPF(e + 1.0f);
}

extern "C" __global__ void prep_kernel(const float* __restrict__ W_emb,
                                       const float* __restrict__ W_ih,
                                       const float* __restrict__ b_ih,
                                       const float* __restrict__ W_hh,
                                       const float* __restrict__ b_hh,
                                       float* __restrict__ ws) {
    int tid = blockIdx.x * blockDim.x + threadIdx.x;
    int nth = gridDim.x * blockDim.x;
    __half* WF    = (__half*)ws;
    __half* WG    = (__half*)ws + WS_WGF_H;
    float*  biasc = ws + WS_BIAS_F;
    for (int i = tid; i < 32768; i += nth) {
        int kg = i >> 10, m = (i >> 3) & 127, j = i & 7;
        WF[i] = __float2half(W_emb[m * 256 + kg * 8 + j]);
    }
    for (int i = tid; i < 131072; i += nth) {
        int kc = i >> 12, g = (i >> 3) & 511, j = i & 7;
        int k = kc * 8 + j;
        float w = (k < 128) ? W_ih[g * 128 + k] : W_hh[g * 128 + (k - 128)];
        WG[i] = __float2half(w);
    }
    for (int i = tid; i < 512; i += nth) biasc[i] = b_ih[i] + b_hh[i];
}

extern "C" __global__ __launch_bounds__(1024, 4)
void set2vec_main(const float* __restrict__ hidden,
                  const float* __restrict__ input,
                  const float* __restrict__ b_emb,
                  const unsigned char* __restrict__ mask_bytes,
                  const int* __restrict__ Tptr,
                  const float* __restrict__ ws,
                  float* __restrict__ out) {
    __shared__ __half2 mem2[NB][NN][MP2];    // 54400 B fp16 memory [bb][n][m-pair]
    __shared__ __half  xcath[NB][XPAD];      // fp16 [lstm_in | h] (MFMA A operand)
    __shared__ float   xcat2[NB][KD];        // fp32 [lstm_in | h]
    __shared__ float   cbuf[NB][MD];
    __shared__ float   emask[NB][NN];
    __shared__ float   bbuf[G4];
    __shared__ int     mask_is_u8;
    __shared__ float   gbuf[NB][G4];         // gates output
    __shared__ float   ebuf[NB][128];        // energies output (mask folded in)
    __shared__ float   abuf[NB][NN];         // attn weights

    const int tid  = threadIdx.x;
    const int b0   = blockIdx.x * NB;
    const int lane = tid & 63, wv = tid >> 6;
    const int ln15 = lane & 15, lhi = lane >> 4;
    const __half* WF   = (const __half*)ws;
    const __half* memh = (const __half*)mem2;

    if (tid == 0) {
        int nz = 0;
        for (int i = 0; i < 64; ++i)
            if ((i & 3) && mask_bytes[i]) nz = 1;
        mask_is_u8 = nz;
    }

    // ---- fused embed via MFMA: mem = fp16(cat(hidden,input) @ W_emb^T + b_emb) ----
    {
        const float be0 = b_emb[0 * 16 + ln15], be1 = b_emb[1 * 16 + ln15];
        const float be2 = b_emb[2 * 16 + ln15], be3 = b_emb[3 * 16 + ln15];
        const float be4 = b_emb[4 * 16 + ln15], be5 = b_emb[5 * 16 + ln15];
        const float be6 = b_emb[6 * 16 + ln15], be7 = b_emb[7 * 16 + ln15];
        __half* memw = (__half*)mem2;
        const int tile = wv;                  // 13 row-tiles of 16 (NB*NN = 200)
        if (tile < 13) {
            f32x4 acc0 = {be0, be0, be0, be0}, acc1 = {be1, be1, be1, be1};
            f32x4 acc2 = {be2, be2, be2, be2}, acc3 = {be3, be3, be3, be3};
            f32x4 acc4 = {be4, be4, be4, be4}, acc5 = {be5, be5, be5, be5};
            f32x4 acc6 = {be6, be6, be6, be6}, acc7 = {be7, be7, be7, be7};

            const int rA     = tile * 16 + ln15;
            const int rAok   = rA < NB * NN;
            const long gbase = ((long)(b0 * NN + rA)) << 7;

            #pragma unroll 1
            for (int mk = 0; mk < 8; ++mk) {
                f16x8 aF;
                if (rAok) {
                    int k0 = mk * 32 + lhi * 8;
                    const float* src = (k0 < 128) ? (hidden + gbase + k0)
                                                  : (input + gbase + (k0 - 128));
                    float4 v0 = *(const float4*)src;
                    float4 v1 = *(const float4*)(src + 4);
                    union { f16x8 v; unsigned u[4]; } au;
                    au.u[0] = PKRTZ(v0.x, v0.y);
                    au.u[1] = PKRTZ(v0.z, v0.w);
                    au.u[2] = PKRTZ(v1.x, v1.y);
                    au.u[3] = PKRTZ(v1.z, v1.w);
                    aF = au.v;
                } else {
                    aF = (f16x8)(_Float16)0.0f;
                }
                const __half* wrow = WF + ((mk * 4 + lhi) * 128 + ln15) * 8;
#define EMB_CT(CT, ACC) { \
                union { uint4 u; f16x8 v; } bu; \
                bu.u = *(const uint4*)(wrow + (CT * 16) * 8); \
                ACC = __builtin_amdgcn_mfma_f32_16x16x32_f16(aF, bu.v, ACC, 0, 0, 0); }
                EMB_CT(0, acc0) EMB_CT(1, acc1) EMB_CT(2, acc2) EMB_CT(3, acc3)
                EMB_CT(4, acc4) EMB_CT(5, acc5) EMB_CT(6, acc6) EMB_CT(7, acc7)
#undef EMB_CT
            }
#define EMB_WR(CT, ACC) { \
            _Pragma("unroll") \
            for (int reg = 0; reg < 4; ++reg) { \
                int r = tile * 16 + lhi * 4 + reg; \
                if (r < NB * NN) { \
                    int bb = r / NN, n = r - (r / NN) * NN; \
                    memw[(bb * NN + n) * (2 * MP2) + CT * 16 + ln15] = __float2half(ACC[reg]); \
                } } }
            EMB_WR(0, acc0) EMB_WR(1, acc1) EMB_WR(2, acc2) EMB_WR(3, acc3)
            EMB_WR(4, acc4) EMB_WR(5, acc5) EMB_WR(6, acc6) EMB_WR(7, acc7)
#undef EMB_WR
        }
    }

    // ---- gate weight pointers (streamed from L2 each step) ----
    const uint4* WgB = (const uint4*)((const __half*)ws + WS_WGF_H);
    const int ct0 = wv * 2, ct1 = wv * 2 + 1;

    // ---- init LSTM state + mask + bias tables ----
    for (int i = tid; i < NB * XPAD; i += 1024) ((__half*)xcath)[i] = __float2half(0.0f);
    if (tid < NB * KD) ((float*)xcat2)[tid] = 0.0f;
    if (tid < NB * MD) ((float*)cbuf)[tid] = 0.0f;
    if (tid < G4) bbuf[tid] = ws[WS_BIAS_F + tid];
    if (tid < NB * NN) {
        int bb = tid / NN, n = tid - bb * NN;
        long mrow = (long)(b0 + bb) * NN + n;
        int valid = mask_is_u8 ? (mask_bytes[mrow] != 0)
                               : (((const int*)mask_bytes)[mrow] != 0);
        emask[bb][n] = valid ? 0.0f : BIG_NEG;
    }
    __syncthreads();

    const int T = Tptr[0];

    // ---- per-thread phase constants ----
    const __half* aBase = &xcath[ln15 & 1][lhi * 8];   // batch 0/1 on even/odd A rows

    // energies: wave wv<14 handles pair (bb, ntile) = (wv/7, wv%7)
    const int e_bb = (wv < 14) ? (wv / 7) : 0;
    const int e_nt = (wv < 14) ? (wv - e_bb * 7) : 0;
    const int e_n  = e_nt * 16 + ln15;
    const int e_nc = (e_n < 100) ? e_n : 99;           // clamp OOB (result discarded)
    const __half* eB = memh + (e_bb * NN + e_nc) * (2 * MP2) + lhi * 8;
    const __half* eA = &xcath[e_bb][128 + lhi * 8];

    // fused softmax+read: 8 waves, wave = (bb = wv>>2, mq = wv&3)
    // lane = rg*4 + rs: rg = n-group (4x7 + 12x6), rs = m-slice of 8 within the 32-m quarter
    const int sr_bb = (wv >> 2) & 1, sr_mq = wv & 3;
    const int rg = lane >> 2, rs = lane & 3;
    const int r_start = (rg < 4) ? rg * 7 : 28 + (rg - 4) * 6;
    const int r_cnt   = (rg < 4) ? 7 : 6;
    const __half* rB = memh + sr_bb * NN * (2 * MP2) + sr_mq * 32 + rs * 8;

    for (int step = 0; step < T; ++step) {
        // --- gates via MFMA: X[2,256] @ Wcat^T -> gbuf[2][512] ---
        {
            f32x4 ga = {0.f, 0.f, 0.f, 0.f}, gb = {0.f, 0.f, 0.f, 0.f};
#define GS(KS) { \
            union { uint4 u; f16x8 v; } a, ba, bc; \
            a.u  = *(const uint4*)(aBase + (KS) * 32); \
            ba.u = WgB[((KS) * 4 + lhi) * 512 + ct0 * 16 + ln15]; \
            bc.u = WgB[((KS) * 4 + lhi) * 512 + ct1 * 16 + ln15]; \
            ga = __builtin_amdgcn_mfma_f32_16x16x32_f16(a.v, ba.v, ga, 0, 0, 0); \
            gb = __builtin_amdgcn_mfma_f32_16x16x32_f16(a.v, bc.v, gb, 0, 0, 0); }
            GS(0) GS(1) GS(2) GS(3) GS(4) GS(5) GS(6) GS(7)
#undef GS
            if (lhi == 0) {   // D rows 0,1 = batches 0,1
                gbuf[0][ct0 * 16 + ln15] = ga[0];
                gbuf[1][ct0 * 16 + ln15] = ga[1];
                gbuf[0][ct1 * 16 + ln15] = gb[0];
                gbuf[1][ct1 * 16 + ln15] = gb[1];
            }
        }
        __syncthreads();
        // --- LSTM pointwise (i,f,g,o), fast transcendentals ---
        if (tid < NB * MD) {
            int bb = tid >> 7, m = tid & 127;
            float gi = gbuf[bb][m]       + bbuf[m];
            float gf = gbuf[bb][128 + m] + bbuf[128 + m];
            float gg = gbuf[bb][256 + m] + bbuf[256 + m];
            float go = gbuf[bb][384 + m] + bbuf[384 + m];
            float c  = cbuf[bb][m];
            c = sigm(gf) * c + sigm(gi) * tanh_f(gg);
            float qv = sigm(go) * tanh_f(c);
            cbuf[bb][m] = c;
            xcat2[bb][128 + m] = qv;
            xcath[bb][128 + m] = __float2half(qv);
        }
        __syncthreads();
        // --- energies via per-batch MFMA (A-rows broadcast = q_bb); emask folded in ---
        if (wv < 14) {
            f32x4 e0 = {0.f, 0.f, 0.f, 0.f};
#define ES(KS) { \
            union { uint4 u; f16x8 v; } a0, bq0; \
            a0.u  = *(const uint4*)(eA + (KS) * 32); \
            bq0.u = *(const uint4*)(eB + (KS) * 32); \
            e0 = __builtin_amdgcn_mfma_f32_16x16x32_f16(a0.v, bq0.v, e0, 0, 0, 0); }
            ES(0) ES(1) ES(2) ES(3)
#undef ES
            if (lhi == 0 && e_n < 100)
                ebuf[e_bb][e_n] = e0[0] + emask[e_bb][e_n];
        }
        __syncthreads();
        // --- fused softmax+read: 8 waves (4 per bb, redundant softmax) ---
        if (wv < 8) {
            {
                float e0 = ebuf[sr_bb][lane];
                float e1 = (lane < 36) ? ebuf[sr_bb][64 + lane] : -INFINITY;
                float mx = fmaxf(e0, e1);
                for (int off = 32; off; off >>= 1) mx = fmaxf(mx, __shfl_xor(mx, off, 64));
                float p0 = __expf(e0 - mx);
                float p1 = (lane < 36) ? __expf(e1 - mx) : 0.0f;
                float s = p0 + p1;
                for (int off = 32; off; off >>= 1) s += __shfl_xor(s, off, 64);
                float inv = RCPF(s);
                abuf[sr_bb][lane] = p0 * inv;
                if (lane < 36) abuf[sr_bb][64 + lane] = p1 * inv;
            }
            // read: lane accumulates its n-group (<=7) over its 8-half m-slice
            float a0 = 0.f, a1 = 0.f, a2 = 0.f, a3 = 0.f;
            float a4 = 0.f, a5 = 0.f, a6 = 0.f, a7 = 0.f;
            #pragma unroll
            for (int j = 0; j < 7; ++j) {
                if (j < r_cnt) {
                    int n = r_start + j;
                    float av = abuf[sr_bb][n];
                    uint4 u  = *(const uint4*)(rB + n * (2 * MP2));
                    float2 f0 = __half22float2(*(__half2*)&u.x);
                    float2 f1 = __half22float2(*(__half2*)&u.y);
                    float2 f2 = __half22float2(*(__half2*)&u.z);
                    float2 f3 = __half22float2(*(__half2*)&u.w);
                    a0 = fmaf(av, f0.x, a0); a1 = fmaf(av, f0.y, a1);
                    a2 = fmaf(av, f1.x, a2); a3 = fmaf(av, f1.y, a3);
                    a4 = fmaf(av, f2.x, a4); a5 = fmaf(av, f2.y, a5);
                    a6 = fmaf(av, f3.x, a6); a7 = fmaf(av, f3.y, a7);
                }
            }
#define RED(A) A += __shfl_xor(A, 4, 64); A += __shfl_xor(A, 8, 64); \
               A += __shfl_xor(A, 16, 64); A += __shfl_xor(A, 32, 64);
            RED(a0) RED(a1) RED(a2) RED(a3) RED(a4) RED(a5) RED(a6) RED(a7)
#undef RED
            if (lane < 4) {     // rg == 0 lanes hold full sums; rs == lane
                int m = sr_mq * 32 + lane * 8;
                float4 lo = {a0, a1, a2, a3}, hi = {a4, a5, a6, a7};
                *(float4*)&xcat2[sr_bb][m]     = lo;
                *(float4*)&xcat2[sr_bb][m + 4] = hi;
                uint4 hv;
                hv.x = PKRTZ(a0, a1);
                hv.y = PKRTZ(a2, a3);
                hv.z = PKRTZ(a4, a5);
                hv.w = PKRTZ(a6, a7);
                *(uint4*)&xcath[sr_bb][m] = hv;
            }
        }
        __syncthreads();
    }

    // ---- output: [q | read], 2 batches x 256 ----
    if (tid < NB * 256) {
        int bb = tid >> 8, j = tid & 255;
        float v = (j < 128) ? xcat2[bb][128 + j] : xcat2[bb][j - 128];
        out[((long)(b0 + bb) << 8) + j] = v;
    }
}

extern "C" void kernel_launch(void* const* d_in, const int* in_sizes, int n_in,
                              void* d_out, int out_size, void* d_ws, size_t ws_size,
                              hipStream_t stream) {
    const float* hidden = (const float*)d_in[0];
    const float* input  = (const float*)d_in[1];
    const float* W_emb  = (const float*)d_in[2];
    const float* b_emb  = (const float*)d_in[3];
    const float* W_ih   = (const float*)d_in[4];
    const float* b_ih   = (const float*)d_in[5];
    const float* W_hh   = (const float*)d_in[6];
    const float* b_hh   = (const float*)d_in[7];
    const unsigned char* mask = (const unsigned char*)d_in[8];
    const int*  Tptr    = (const int*)d_in[9];
    float* ws   = (float*)d_ws;
    float* outp = (float*)d_out;

    hipLaunchKernelGGL(prep_kernel, dim3(128), dim3(256), 0, stream,
                       W_emb, W_ih, b_ih, W_hh, b_hh, ws);
    hipLaunchKernelGGL(set2vec_main, dim3(1024), dim3(1024), 0, stream,
                       hidden, input, b_emb, mask, Tptr, ws, outp);
}

// Round 15
// 206.817 us; speedup vs baseline: 1.1436x; 1.1436x over previous
//
#include <hip/hip_runtime.h>
#include <hip/hip_fp16.h>
#include <math.h>

#define BIG_NEG  (-1.0e6f)
#define NN   100
#define MD   128
#define KD   256
#define G4   512
#define NB   4    // batch elements per block
#define MP2  68   // __half2 stride per mem row (272 B, 16B-aligned)
#define XPAD 288  // xh row stride in halves

// ws layout:
//   halves [0, 32768)       : WembF embed B-frags [kg:32][m:128][j:8]
//   halves [32768, 163840)  : WGF gates B-frags, PERMUTED cols gp=m*4+gate:
//                             WG[((kc*512)+gp)*8+j] = Wcat[k=kc*8+j][g=(gp&3)*128+(gp>>2)]
//   floats [81920, 82432)   : biasc[gp] = (b_ih+b_hh)[(gp&3)*128+(gp>>2)]
#define WS_WGF_H  32768
#define WS_BIAS_F 81920

typedef _Float16 f16x2 __attribute__((ext_vector_type(2)));
typedef _Float16 f16x8 __attribute__((ext_vector_type(8)));
typedef float    f32x4 __attribute__((ext_vector_type(4)));

#if __has_builtin(__builtin_amdgcn_rcpf)
#define RCPF(x) __builtin_amdgcn_rcpf(x)
#else
#define RCPF(x) (1.0f / (x))
#endif

#define PKRTZ(a, b) __builtin_bit_cast(unsigned, __builtin_amdgcn_cvt_pkrtz((a), (b)))

__device__ __forceinline__ float sigm(float x) {
    return RCPF(1.0f + __expf(-x));
}
__device__ __forceinline__ float tanh_f(float x) {
    float xc = fminf(fmaxf(x, -15.0f), 15.0f);
    float e  = __expf(2.0f * xc);
    return (e - 1.0f) * RCPF(e + 1.0f);
}

extern "C" __global__ void prep_kernel(const float* __restrict__ W_emb,
                                       const float* __restrict__ W_ih,
                                       const float* __restrict__ b_ih,
                                       const float* __restrict__ W_hh,
                                       const float* __restrict__ b_hh,
                                       float* __restrict__ ws) {
    int tid = blockIdx.x * blockDim.x + threadIdx.x;
    int nth = gridDim.x * blockDim.x;
    __half* WF    = (__half*)ws;
    __half* WG    = (__half*)ws + WS_WGF_H;
    float*  biasc = ws + WS_BIAS_F;
    for (int i = tid; i < 32768; i += nth) {
        int kg = i >> 10, m = (i >> 3) & 127, j = i & 7;
        WF[i] = __float2half(W_emb[m * 256 + kg * 8 + j]);
    }
    for (int i = tid; i < 131072; i += nth) {
        int kc = i >> 12, gp = (i >> 3) & 511, j = i & 7;
        int k = kc * 8 + j;
        int g = (gp & 3) * 128 + (gp >> 2);      // gate-major original row
        float w = (k < 128) ? W_ih[g * 128 + k] : W_hh[g * 128 + (k - 128)];
        WG[i] = __float2half(w);
    }
    for (int i = tid; i < 512; i += nth) {
        int g = (i & 3) * 128 + (i >> 2);
        biasc[i] = b_ih[g] + b_hh[g];
    }
}

extern "C" __global__ __launch_bounds__(1024, 4)
void set2vec_main(const float* __restrict__ hidden,
                  const float* __restrict__ input,
                  const float* __restrict__ b_emb,
                  const unsigned char* __restrict__ mask_bytes,
                  const int* __restrict__ Tptr,
                  const float* __restrict__ ws,
                  float* __restrict__ out) {
    __shared__ __half2 mem2[NB][NN][MP2];    // 108800 B fp16 memory [bb][n][m-pair]
    __shared__ __half  xh[2][NB][XPAD];      // double-buffered fp16 [lstm_in | h]
    __shared__ float   xcat2[NB][KD];        // fp32 [lstm_in | h] (for output)
    __shared__ float   cbuf[NB][MD];
    __shared__ float   emask[NB][NN];
    __shared__ float   bbuf[G4];             // permuted bias
    __shared__ int     mask_is_u8;
    __shared__ float   ebuf[NB][128];        // energies (mask folded in)
    __shared__ float   abuf[NB][NN];         // attn weights

    const int tid  = threadIdx.x;
    const int b0   = blockIdx.x * NB;
    const int lane = tid & 63, wv = tid >> 6;
    const int ln15 = lane & 15, lhi = lane >> 4;
    const __half* WF   = (const __half*)ws;
    const __half* memh = (const __half*)mem2;

    if (tid == 0) {
        int nz = 0;
        for (int i = 0; i < 64; ++i)
            if ((i & 3) && mask_bytes[i]) nz = 1;
        mask_is_u8 = nz;
    }

    // ---- fused embed via MFMA: mem = fp16(cat(hidden,input) @ W_emb^T + b_emb) ----
    {
        const float be0 = b_emb[0 * 16 + ln15], be1 = b_emb[1 * 16 + ln15];
        const float be2 = b_emb[2 * 16 + ln15], be3 = b_emb[3 * 16 + ln15];
        const float be4 = b_emb[4 * 16 + ln15], be5 = b_emb[5 * 16 + ln15];
        const float be6 = b_emb[6 * 16 + ln15], be7 = b_emb[7 * 16 + ln15];
        __half* memw = (__half*)mem2;
        for (int tile = wv; tile < 25; tile += 16) {   // 25 row-tiles of 16
            f32x4 acc0 = {be0, be0, be0, be0}, acc1 = {be1, be1, be1, be1};
            f32x4 acc2 = {be2, be2, be2, be2}, acc3 = {be3, be3, be3, be3};
            f32x4 acc4 = {be4, be4, be4, be4}, acc5 = {be5, be5, be5, be5};
            f32x4 acc6 = {be6, be6, be6, be6}, acc7 = {be7, be7, be7, be7};

            const int rA     = tile * 16 + ln15;
            const int rAok   = rA < NB * NN;
            const long gbase = ((long)(b0 * NN + rA)) << 7;

            #pragma unroll 1
            for (int mk = 0; mk < 8; ++mk) {
                f16x8 aF;
                if (rAok) {
                    int k0 = mk * 32 + lhi * 8;
                    const float* src = (k0 < 128) ? (hidden + gbase + k0)
                                                  : (input + gbase + (k0 - 128));
                    float4 v0 = *(const float4*)src;
                    float4 v1 = *(const float4*)(src + 4);
                    union { f16x8 v; unsigned u[4]; } au;
                    au.u[0] = PKRTZ(v0.x, v0.y);
                    au.u[1] = PKRTZ(v0.z, v0.w);
                    au.u[2] = PKRTZ(v1.x, v1.y);
                    au.u[3] = PKRTZ(v1.z, v1.w);
                    aF = au.v;
                } else {
                    aF = (f16x8)(_Float16)0.0f;
                }
                const __half* wrow = WF + ((mk * 4 + lhi) * 128 + ln15) * 8;
#define EMB_CT(CT, ACC) { \
                union { uint4 u; f16x8 v; } bu; \
                bu.u = *(const uint4*)(wrow + (CT * 16) * 8); \
                ACC = __builtin_amdgcn_mfma_f32_16x16x32_f16(aF, bu.v, ACC, 0, 0, 0); }
                EMB_CT(0, acc0) EMB_CT(1, acc1) EMB_CT(2, acc2) EMB_CT(3, acc3)
                EMB_CT(4, acc4) EMB_CT(5, acc5) EMB_CT(6, acc6) EMB_CT(7, acc7)
#undef EMB_CT
            }
#define EMB_WR(CT, ACC) { \
            _Pragma("unroll") \
            for (int reg = 0; reg < 4; ++reg) { \
                int r = tile * 16 + lhi * 4 + reg; \
                if (r < NB * NN) { \
                    int bb = r / NN, n = r - (r / NN) * NN; \
                    memw[(bb * NN + n) * (2 * MP2) + CT * 16 + ln15] = __float2half(ACC[reg]); \
                } } }
            EMB_WR(0, acc0) EMB_WR(1, acc1) EMB_WR(2, acc2) EMB_WR(3, acc3)
            EMB_WR(4, acc4) EMB_WR(5, acc5) EMB_WR(6, acc6) EMB_WR(7, acc7)
#undef EMB_WR
        }
    }

    // ---- gate weights: streamed from L2 each step ----
    const uint4* WgB = (const uint4*)((const __half*)ws + WS_WGF_H);
    const int ct0 = wv * 2, ct1 = wv * 2 + 1;
    const int gp0 = ct0 * 16 + ln15, gp1 = ct1 * 16 + ln15;

    // ---- init LSTM state + mask + bias tables ----
    for (int i = tid; i < 2 * NB * XPAD; i += 1024) ((__half*)xh)[i] = __float2half(0.0f);
    ((float*)xcat2)[tid] = 0.0f;
    if (tid < NB * MD) ((float*)cbuf)[tid] = 0.0f;
    if (tid < G4) bbuf[tid] = ws[WS_BIAS_F + tid];
    if (tid < NB * NN) {
        int bb = tid / NN, n = tid - bb * NN;
        long mrow = (long)(b0 + bb) * NN + n;
        int valid = mask_is_u8 ? (mask_bytes[mrow] != 0)
                               : (((const int*)mask_bytes)[mrow] != 0);
        emask[bb][n] = valid ? 0.0f : BIG_NEG;
    }
    __syncthreads();

    const int T = Tptr[0];

    // ---- per-thread phase constants ----
    const __half* aB0 = &xh[0][ln15 & 3][lhi * 8];     // batch 0-3 on A rows 0-3 (dup'd)
    const __half* aB1 = &xh[1][ln15 & 3][lhi * 8];

    // gates pw: writer lanes (ln15&3)==0; my m values
    const int pw_wr = (ln15 & 3) == 0;
    const int pw_m0 = ct0 * 4 + (ln15 >> 2);
    const int pw_m1 = ct1 * 4 + (ln15 >> 2);

    // energies: wave wv<14 handles pairs (bb,ntile) p=2wv, 2wv+1 of 28
    const int ep0 = wv * 2, ep1 = wv * 2 + 1;
    const int e_bb0 = ep0 / 7, e_nt0 = ep0 - e_bb0 * 7;
    const int e_bb1 = ep1 / 7, e_nt1 = ep1 - e_bb1 * 7;
    const int e_n0  = e_nt0 * 16 + ln15, e_n1 = e_nt1 * 16 + ln15;
    const int e_n0c = (e_n0 < 100) ? e_n0 : 99;
    const int e_n1c = (e_n1 < 100) ? e_n1 : 99;
    const __half* eB0 = memh + (e_bb0 * NN + e_n0c) * (2 * MP2) + lhi * 8;
    const __half* eB1 = memh + (e_bb1 * NN + e_n1c) * (2 * MP2) + lhi * 8;
    const __half* eA00 = &xh[0][e_bb0][128 + lhi * 8];
    const __half* eA01 = &xh[1][e_bb0][128 + lhi * 8];
    const __half* eA10 = &xh[0][e_bb1][128 + lhi * 8];
    const __half* eA11 = &xh[1][e_bb1][128 + lhi * 8];

    // fused softmax+read: 16 waves, wave = (bb = wv>>2, mq = wv&3)
    const int sr_bb = wv >> 2, sr_mq = wv & 3;
    const int rg = lane >> 2, rs = lane & 3;
    const int r_start = (rg < 4) ? rg * 7 : 28 + (rg - 4) * 6;
    const int r_cnt   = (rg < 4) ? 7 : 6;
    const __half* rB = memh + sr_bb * NN * (2 * MP2) + sr_mq * 32 + rs * 8;

#define SHFL4(D, S, MSK) { D[0] = __shfl_xor(S[0], MSK, 64); D[1] = __shfl_xor(S[1], MSK, 64); \
                           D[2] = __shfl_xor(S[2], MSK, 64); D[3] = __shfl_xor(S[3], MSK, 64); }
#define SEL4(V) (lhi == 0 ? V[0] : (lhi == 1 ? V[1] : (lhi == 2 ? V[2] : V[3])))

    for (int step = 0; step < T; ++step) {
        const int sp = step & 1;
        const __half* aB = sp ? aB1 : aB0;
        __half (*xhN)[XPAD] = xh[sp ^ 1];

        // --- gates via MFMA (permuted cols) + in-wave LSTM pointwise ---
        {
            f32x4 ga = {0.f, 0.f, 0.f, 0.f}, gb = {0.f, 0.f, 0.f, 0.f};
#define GS(KS) { \
            union { uint4 u; f16x8 v; } a, ba, bc; \
            a.u  = *(const uint4*)(aB + (KS) * 32); \
            ba.u = WgB[((KS) * 4 + lhi) * 512 + gp0]; \
            bc.u = WgB[((KS) * 4 + lhi) * 512 + gp1]; \
            ga = __builtin_amdgcn_mfma_f32_16x16x32_f16(a.v, ba.v, ga, 0, 0, 0); \
            gb = __builtin_amdgcn_mfma_f32_16x16x32_f16(a.v, bc.v, gb, 0, 0, 0); }
            GS(0) GS(1) GS(2) GS(3) GS(4) GS(5) GS(6) GS(7)
#undef GS
            // bias (own column), then 4-lane butterfly to gather i,f,g,o
            {
                float b0v = bbuf[gp0], b1v = bbuf[gp1];
                ga[0] += b0v; ga[1] += b0v; ga[2] += b0v; ga[3] += b0v;
                gb[0] += b1v; gb[1] += b1v; gb[2] += b1v; gb[3] += b1v;
            }
            f32x4 aV1, aV2, aV3, bV1, bV2, bV3;
            SHFL4(aV1, ga, 1) SHFL4(aV2, ga, 2) SHFL4(aV3, aV1, 2)
            SHFL4(bV1, gb, 1) SHFL4(bV2, gb, 2) SHFL4(bV3, bV1, 2)
            if (pw_wr) {
                // V0=i, V1=f, V2=g, V3=o; batch = lhi (D-rows duplicate mod 4)
                float gi = SEL4(ga),  gf = SEL4(aV1), gg = SEL4(aV2), go = SEL4(aV3);
                float c  = cbuf[lhi][pw_m0];
                c = sigm(gf) * c + sigm(gi) * tanh_f(gg);
                float qv = sigm(go) * tanh_f(c);
                cbuf[lhi][pw_m0] = c;
                xhN[lhi][128 + pw_m0] = __float2half(qv);
                xcat2[lhi][128 + pw_m0] = qv;

                float hi_ = SEL4(gb), hf = SEL4(bV1), hg = SEL4(bV2), ho = SEL4(bV3);
                float c1  = cbuf[lhi][pw_m1];
                c1 = sigm(hf) * c1 + sigm(hi_) * tanh_f(hg);
                float qv1 = sigm(ho) * tanh_f(c1);
                cbuf[lhi][pw_m1] = c1;
                xhN[lhi][128 + pw_m1] = __float2half(qv1);
                xcat2[lhi][128 + pw_m1] = qv1;
            }
        }
        __syncthreads();
        // --- energies via per-batch MFMA (A-rows broadcast = q_bb); emask folded ---
        if (wv < 14) {
            const __half* eA0 = sp ? eA01 : eA00;   // note: q lives in buf sp^1
            const __half* eA1 = sp ? eA11 : eA10;
            eA0 = (sp ^ 1) ? eA01 : eA00;
            eA1 = (sp ^ 1) ? eA11 : eA10;
            f32x4 e0 = {0.f, 0.f, 0.f, 0.f}, e1 = {0.f, 0.f, 0.f, 0.f};
#define ES(KS) { \
            union { uint4 u; f16x8 v; } a0, a1, bq0, bq1; \
            a0.u  = *(const uint4*)(eA0 + (KS) * 32); \
            bq0.u = *(const uint4*)(eB0 + (KS) * 32); \
            a1.u  = *(const uint4*)(eA1 + (KS) * 32); \
            bq1.u = *(const uint4*)(eB1 + (KS) * 32); \
            e0 = __builtin_amdgcn_mfma_f32_16x16x32_f16(a0.v, bq0.v, e0, 0, 0, 0); \
            e1 = __builtin_amdgcn_mfma_f32_16x16x32_f16(a1.v, bq1.v, e1, 0, 0, 0); }
            ES(0) ES(1) ES(2) ES(3)
#undef ES
            if (lhi == 0) {
                if (e_n0 < 100) ebuf[e_bb0][e_n0] = e0[0] + emask[e_bb0][e_n0];
                if (e_n1 < 100) ebuf[e_bb1][e_n1] = e1[0] + emask[e_bb1][e_n1];
            }
        }
        __syncthreads();
        // --- fused softmax+read: 16 waves (4 per bb, redundant softmax) ---
        {
            {
                float e0 = ebuf[sr_bb][lane];
                float e1 = (lane < 36) ? ebuf[sr_bb][64 + lane] : -INFINITY;
                float mx = fmaxf(e0, e1);
                for (int off = 32; off; off >>= 1) mx = fmaxf(mx, __shfl_xor(mx, off, 64));
                float p0 = __expf(e0 - mx);
                float p1 = (lane < 36) ? __expf(e1 - mx) : 0.0f;
                float s = p0 + p1;
                for (int off = 32; off; off >>= 1) s += __shfl_xor(s, off, 64);
                float inv = RCPF(s);
                abuf[sr_bb][lane] = p0 * inv;
                if (lane < 36) abuf[sr_bb][64 + lane] = p1 * inv;
            }
            float a0 = 0.f, a1 = 0.f, a2 = 0.f, a3 = 0.f;
            float a4 = 0.f, a5 = 0.f, a6 = 0.f, a7 = 0.f;
            #pragma unroll
            for (int j = 0; j < 7; ++j) {
                if (j < r_cnt) {
                    int n = r_start + j;
                    float av = abuf[sr_bb][n];
                    uint4 u  = *(const uint4*)(rB + n * (2 * MP2));
                    float2 f0 = __half22float2(*(__half2*)&u.x);
                    float2 f1 = __half22float2(*(__half2*)&u.y);
                    float2 f2 = __half22float2(*(__half2*)&u.z);
                    float2 f3 = __half22float2(*(__half2*)&u.w);
                    a0 = fmaf(av, f0.x, a0); a1 = fmaf(av, f0.y, a1);
                    a2 = fmaf(av, f1.x, a2); a3 = fmaf(av, f1.y, a3);
                    a4 = fmaf(av, f2.x, a4); a5 = fmaf(av, f2.y, a5);
                    a6 = fmaf(av, f3.x, a6); a7 = fmaf(av, f3.y, a7);
                }
            }
#define RED(A) A += __shfl_xor(A, 4, 64); A += __shfl_xor(A, 8, 64); \
               A += __shfl_xor(A, 16, 64); A += __shfl_xor(A, 32, 64);
            RED(a0) RED(a1) RED(a2) RED(a3) RED(a4) RED(a5) RED(a6) RED(a7)
#undef RED
            if (lane < 4) {     // rg==0 lanes hold full sums; rs == lane
                int m = sr_mq * 32 + lane * 8;
                float4 lo = {a0, a1, a2, a3}, hi = {a4, a5, a6, a7};
                *(float4*)&xcat2[sr_bb][m]     = lo;
                *(float4*)&xcat2[sr_bb][m + 4] = hi;
                uint4 hv;
                hv.x = PKRTZ(a0, a1);
                hv.y = PKRTZ(a2, a3);
                hv.z = PKRTZ(a4, a5);
                hv.w = PKRTZ(a6, a7);
                *(uint4*)&xhN[sr_bb][m] = hv;
            }
        }
        __syncthreads();
    }

    // ---- output: [q | read], 4 batches x 256 ----
    {
        int bb = tid >> 8, j = tid & 255;
        float v = (j < 128) ? xcat2[bb][128 + j] : xcat2[bb][j - 128];
        out[((long)(b0 + bb) << 8) + j] = v;
    }
}

extern "C" void kernel_launch(void* const* d_in, const int* in_sizes, int n_in,
                              void* d_out, int out_size, void* d_ws, size_t ws_size,
                              hipStream_t stream) {
    const float* hidden = (const float*)d_in[0];
    const float* input  = (const float*)d_in[1];
    const float* W_emb  = (const float*)d_in[2];
    const float* b_emb  = (const float*)d_in[3];
    const float* W_ih   = (const float*)d_in[4];
    const float* b_ih   = (const float*)d_in[5];
    const float* W_hh   = (const float*)d_in[6];
    const float* b_hh   = (const float*)d_in[7];
    const unsigned char* mask = (const unsigned char*)d_in[8];
    const int*  Tptr    = (const int*)d_in[9];
    float* ws   = (float*)d_ws;
    float* outp = (float*)d_out;

    hipLaunchKernelGGL(prep_kernel, dim3(128), dim3(256), 0, stream,
                       W_emb, W_ih, b_ih, W_hh, b_hh, ws);
    hipLaunchKernelGGL(set2vec_main, dim3(512), dim3(1024), 0, stream,
                       hidden, input, b_emb, mask, Tptr, ws, outp);
}

// Round 16
// 182.459 us; speedup vs baseline: 1.2963x; 1.1335x over previous
//
#include <hip/hip_runtime.h>
#include <hip/hip_fp16.h>
#include <math.h>

#define BIG_NEG  (-1.0e6f)
#define NN   100
#define MD   128
#define KD   256
#define G4   512
#define NB   4    // batch elements per block
#define MP2  68   // __half2 stride per mem row (272 B, 16B-aligned)
#define XPAD 288  // xcath row stride in halves

// ws layout:
//   halves [0, 32768)       : WembF embed B-frags [kg:32][m:128][j:8]
//   halves [32768, 163840)  : WGF gates B-frags [kc:32][g:512][j:8], k = kc*8+j
//   floats [81920, 82432)   : biasc = b_ih + b_hh
#define WS_WGF_H  32768
#define WS_BIAS_F 81920

typedef _Float16 f16x2 __attribute__((ext_vector_type(2)));
typedef _Float16 f16x8 __attribute__((ext_vector_type(8)));
typedef float    f32x4 __attribute__((ext_vector_type(4)));

#if __has_builtin(__builtin_amdgcn_rcpf)
#define RCPF(x) __builtin_amdgcn_rcpf(x)
#else
#define RCPF(x) (1.0f / (x))
#endif

#define PKRTZ(a, b) __builtin_bit_cast(unsigned, __builtin_amdgcn_cvt_pkrtz((a), (b)))

__device__ __forceinline__ float sigm(float x) {
    return RCPF(1.0f + __expf(-x));          // x<<0: exp=inf -> rcp=0, no NaN
}
__device__ __forceinline__ float tanh_f(float x) {
    float xc = fminf(fmaxf(x, -15.0f), 15.0f);
    float e  = __expf(2.0f * xc);
    return (e - 1.0f) * RCPF(e + 1.0f);
}

extern "C" __global__ void prep_kernel(const float* __restrict__ W_emb,
                                       const float* __restrict__ W_ih,
                                       const float* __restrict__ b_ih,
                                       const float* __restrict__ W_hh,
                                       const float* __restrict__ b_hh,
                                       float* __restrict__ ws) {
    int tid = blockIdx.x * blockDim.x + threadIdx.x;
    int nth = gridDim.x * blockDim.x;
    __half* WF    = (__half*)ws;
    __half* WG    = (__half*)ws + WS_WGF_H;
    float*  biasc = ws + WS_BIAS_F;
    for (int i = tid; i < 32768; i += nth) {
        int kg = i >> 10, m = (i >> 3) & 127, j = i & 7;
        WF[i] = __float2half(W_emb[m * 256 + kg * 8 + j]);
    }
    for (int i = tid; i < 131072; i += nth) {
        int kc = i >> 12, g = (i >> 3) & 511, j = i & 7;
        int k = kc * 8 + j;
        float w = (k < 128) ? W_ih[g * 128 + k] : W_hh[g * 128 + (k - 128)];
        WG[i] = __float2half(w);
    }
    for (int i = tid; i < 512; i += nth) biasc[i] = b_ih[i] + b_hh[i];
}

extern "C" __global__ __launch_bounds__(1024, 4)
void set2vec_main(const float* __restrict__ hidden,
                  const float* __restrict__ input,
                  const float* __restrict__ b_emb,
                  const unsigned char* __restrict__ mask_bytes,
                  const int* __restrict__ Tptr,
                  const float* __restrict__ ws,
                  float* __restrict__ out) {
    __shared__ __half2 mem2[NB][NN][MP2];    // 108800 B fp16 memory [bb][n][m-pair]
    __shared__ __half  xcath[NB][XPAD];      // fp16 [lstm_in | h] (MFMA A operand)
    __shared__ float   xcat2[NB][KD];        // fp32 [lstm_in | h]
    __shared__ float   cbuf[NB][MD];
    __shared__ float   emask[NB][NN];
    __shared__ float   bbuf[G4];
    __shared__ int     mask_is_u8;
    __shared__ float   gbuf[NB][G4];         // gates output
    __shared__ float   ebuf[NB][128];        // energies output (mask folded in)
    __shared__ float   abuf[NB][NN];         // attn weights

    const int tid  = threadIdx.x;
    const int b0   = blockIdx.x * NB;
    const int lane = tid & 63, wv = tid >> 6;
    const int ln15 = lane & 15, lhi = lane >> 4;
    const __half* WF   = (const __half*)ws;
    const __half* memh = (const __half*)mem2;

    if (tid == 0) {
        int nz = 0;
        for (int i = 0; i < 64; ++i)
            if ((i & 3) && mask_bytes[i]) nz = 1;
        mask_is_u8 = nz;
    }

    // ---- fused embed via MFMA: mem = fp16(cat(hidden,input) @ W_emb^T + b_emb) ----
    {
        const float be0 = b_emb[0 * 16 + ln15], be1 = b_emb[1 * 16 + ln15];
        const float be2 = b_emb[2 * 16 + ln15], be3 = b_emb[3 * 16 + ln15];
        const float be4 = b_emb[4 * 16 + ln15], be5 = b_emb[5 * 16 + ln15];
        const float be6 = b_emb[6 * 16 + ln15], be7 = b_emb[7 * 16 + ln15];
        __half* memw = (__half*)mem2;
        for (int tile = wv; tile < 25; tile += 16) {   // 25 row-tiles of 16
            f32x4 acc0 = {be0, be0, be0, be0}, acc1 = {be1, be1, be1, be1};
            f32x4 acc2 = {be2, be2, be2, be2}, acc3 = {be3, be3, be3, be3};
            f32x4 acc4 = {be4, be4, be4, be4}, acc5 = {be5, be5, be5, be5};
            f32x4 acc6 = {be6, be6, be6, be6}, acc7 = {be7, be7, be7, be7};

            const int rA     = tile * 16 + ln15;
            const int rAok   = rA < NB * NN;
            const long gbase = ((long)(b0 * NN + rA)) << 7;

            #pragma unroll 1
            for (int mk = 0; mk < 8; ++mk) {
                f16x8 aF;
                if (rAok) {
                    int k0 = mk * 32 + lhi * 8;
                    const float* src = (k0 < 128) ? (hidden + gbase + k0)
                                                  : (input + gbase + (k0 - 128));
                    float4 v0 = *(const float4*)src;
                    float4 v1 = *(const float4*)(src + 4);
                    union { f16x8 v; unsigned u[4]; } au;
                    au.u[0] = PKRTZ(v0.x, v0.y);
                    au.u[1] = PKRTZ(v0.z, v0.w);
                    au.u[2] = PKRTZ(v1.x, v1.y);
                    au.u[3] = PKRTZ(v1.z, v1.w);
                    aF = au.v;
                } else {
                    aF = (f16x8)(_Float16)0.0f;
                }
                const __half* wrow = WF + ((mk * 4 + lhi) * 128 + ln15) * 8;
#define EMB_CT(CT, ACC) { \
                union { uint4 u; f16x8 v; } bu; \
                bu.u = *(const uint4*)(wrow + (CT * 16) * 8); \
                ACC = __builtin_amdgcn_mfma_f32_16x16x32_f16(aF, bu.v, ACC, 0, 0, 0); }
                EMB_CT(0, acc0) EMB_CT(1, acc1) EMB_CT(2, acc2) EMB_CT(3, acc3)
                EMB_CT(4, acc4) EMB_CT(5, acc5) EMB_CT(6, acc6) EMB_CT(7, acc7)
#undef EMB_CT
            }
#define EMB_WR(CT, ACC) { \
            _Pragma("unroll") \
            for (int reg = 0; reg < 4; ++reg) { \
                int r = tile * 16 + lhi * 4 + reg; \
                if (r < NB * NN) { \
                    int bb = r / NN, n = r - (r / NN) * NN; \
                    memw[(bb * NN + n) * (2 * MP2) + CT * 16 + ln15] = __float2half(ACC[reg]); \
                } } }
            EMB_WR(0, acc0) EMB_WR(1, acc1) EMB_WR(2, acc2) EMB_WR(3, acc3)
            EMB_WR(4, acc4) EMB_WR(5, acc5) EMB_WR(6, acc6) EMB_WR(7, acc7)
#undef EMB_WR
        }
    }

    // ---- gate weight pointers (streamed from L2 each step) ----
    const uint4* WgB = (const uint4*)((const __half*)ws + WS_WGF_H);
    const int ct0 = wv * 2, ct1 = wv * 2 + 1;

    // ---- init LSTM state + mask + bias tables ----
    for (int i = tid; i < NB * XPAD; i += 1024) ((__half*)xcath)[i] = __float2half(0.0f);
    ((float*)xcat2)[tid] = 0.0f;                       // NB*KD = 1024
    if (tid < NB * MD) ((float*)cbuf)[tid] = 0.0f;
    if (tid < G4) bbuf[tid] = ws[WS_BIAS_F + tid];
    if (tid < NB * NN) {
        int bb = tid / NN, n = tid - bb * NN;
        long mrow = (long)(b0 + bb) * NN + n;
        int valid = mask_is_u8 ? (mask_bytes[mrow] != 0)
                               : (((const int*)mask_bytes)[mrow] != 0);
        emask[bb][n] = valid ? 0.0f : BIG_NEG;
    }
    __syncthreads();

    const int T = Tptr[0];

    // ---- per-thread phase constants ----
    const __half* aBase = &xcath[ln15 & 3][lhi * 8];   // batch 0-3 on A rows 0-3 (dup'd)

    // energies: wave wv<14 handles pairs (bb,ntile) p=2wv, 2wv+1 of 28
    const int ep0 = wv * 2, ep1 = wv * 2 + 1;
    const int e_bb0 = ep0 / 7, e_nt0 = ep0 - e_bb0 * 7;
    const int e_bb1 = ep1 / 7, e_nt1 = ep1 - e_bb1 * 7;
    const int e_n0  = e_nt0 * 16 + ln15, e_n1 = e_nt1 * 16 + ln15;
    const int e_n0c = (e_n0 < 100) ? e_n0 : 99;        // clamp OOB lanes (result discarded)
    const int e_n1c = (e_n1 < 100) ? e_n1 : 99;
    const __half* eB0 = memh + (e_bb0 * NN + e_n0c) * (2 * MP2) + lhi * 8;
    const __half* eB1 = memh + (e_bb1 * NN + e_n1c) * (2 * MP2) + lhi * 8;
    const __half* eA0 = &xcath[e_bb0][128 + lhi * 8];
    const __half* eA1 = &xcath[e_bb1][128 + lhi * 8];

    // fused softmax+read: 16 waves, wave = (bb = wv>>2, mq = wv&3)
    // lane = rg*4 + rs: rg = n-group (4x7 + 12x6), rs = m-slice of 8 in the 32-m quarter
    const int sr_bb = wv >> 2, sr_mq = wv & 3;
    const int rg = lane >> 2, rs = lane & 3;
    const int r_start = (rg < 4) ? rg * 7 : 28 + (rg - 4) * 6;
    const int r_cnt   = (rg < 4) ? 7 : 6;
    const __half* rB = memh + sr_bb * NN * (2 * MP2) + sr_mq * 32 + rs * 8;

    for (int step = 0; step < T; ++step) {
        // --- gates via MFMA: X[4,256] @ Wcat^T -> gbuf[4][512] ---
        {
            f32x4 ga = {0.f, 0.f, 0.f, 0.f}, gb = {0.f, 0.f, 0.f, 0.f};
#define GS(KS) { \
            union { uint4 u; f16x8 v; } a, ba, bc; \
            a.u  = *(const uint4*)(aBase + (KS) * 32); \
            ba.u = WgB[((KS) * 4 + lhi) * 512 + ct0 * 16 + ln15]; \
            bc.u = WgB[((KS) * 4 + lhi) * 512 + ct1 * 16 + ln15]; \
            ga = __builtin_amdgcn_mfma_f32_16x16x32_f16(a.v, ba.v, ga, 0, 0, 0); \
            gb = __builtin_amdgcn_mfma_f32_16x16x32_f16(a.v, bc.v, gb, 0, 0, 0); }
            GS(0) GS(1) GS(2) GS(3) GS(4) GS(5) GS(6) GS(7)
#undef GS
            if (lhi == 0) {   // D rows 0-3 = batches 0-3
                #pragma unroll
                for (int r = 0; r < 4; ++r) {
                    gbuf[r][ct0 * 16 + ln15] = ga[r];
                    gbuf[r][ct1 * 16 + ln15] = gb[r];
                }
            }
        }
        __syncthreads();
        // --- LSTM pointwise (i,f,g,o), fast transcendentals ---
        if (tid < NB * MD) {
            int bb = tid >> 7, m = tid & 127;
            float gi = gbuf[bb][m]       + bbuf[m];
            float gf = gbuf[bb][128 + m] + bbuf[128 + m];
            float gg = gbuf[bb][256 + m] + bbuf[256 + m];
            float go = gbuf[bb][384 + m] + bbuf[384 + m];
            float c  = cbuf[bb][m];
            c = sigm(gf) * c + sigm(gi) * tanh_f(gg);
            float qv = sigm(go) * tanh_f(c);
            cbuf[bb][m] = c;
            xcat2[bb][128 + m] = qv;
            xcath[bb][128 + m] = __float2half(qv);
        }
        __syncthreads();
        // --- energies via per-batch MFMA (A-rows broadcast = q_bb); emask folded in ---
        if (wv < 14) {
            f32x4 e0 = {0.f, 0.f, 0.f, 0.f}, e1 = {0.f, 0.f, 0.f, 0.f};
#define ES(KS) { \
            union { uint4 u; f16x8 v; } a0, a1, bq0, bq1; \
            a0.u  = *(const uint4*)(eA0 + (KS) * 32); \
            bq0.u = *(const uint4*)(eB0 + (KS) * 32); \
            a1.u  = *(const uint4*)(eA1 + (KS) * 32); \
            bq1.u = *(const uint4*)(eB1 + (KS) * 32); \
            e0 = __builtin_amdgcn_mfma_f32_16x16x32_f16(a0.v, bq0.v, e0, 0, 0, 0); \
            e1 = __builtin_amdgcn_mfma_f32_16x16x32_f16(a1.v, bq1.v, e1, 0, 0, 0); }
            ES(0) ES(1) ES(2) ES(3)
#undef ES
            if (lhi == 0) {
                if (e_n0 < 100) ebuf[e_bb0][e_n0] = e0[0] + emask[e_bb0][e_n0];
                if (e_n1 < 100) ebuf[e_bb1][e_n1] = e1[0] + emask[e_bb1][e_n1];
            }
        }
        __syncthreads();
        // --- fused softmax+read: 16 waves (4 per bb, redundant softmax) ---
        {
            {
                float e0 = ebuf[sr_bb][lane];
                float e1 = (lane < 36) ? ebuf[sr_bb][64 + lane] : -INFINITY;
                float mx = fmaxf(e0, e1);
                for (int off = 32; off; off >>= 1) mx = fmaxf(mx, __shfl_xor(mx, off, 64));
                float p0 = __expf(e0 - mx);
                float p1 = (lane < 36) ? __expf(e1 - mx) : 0.0f;
                float s = p0 + p1;
                for (int off = 32; off; off >>= 1) s += __shfl_xor(s, off, 64);
                float inv = RCPF(s);
                abuf[sr_bb][lane] = p0 * inv;
                if (lane < 36) abuf[sr_bb][64 + lane] = p1 * inv;
            }
            // read: each lane accumulates its n-group (<=7) over its 8-wide m-slice
            float a0 = 0.f, a1 = 0.f, a2 = 0.f, a3 = 0.f;
            float a4 = 0.f, a5 = 0.f, a6 = 0.f, a7 = 0.f;
            #pragma unroll
            for (int j = 0; j < 7; ++j) {
                if (j < r_cnt) {
                    int n = r_start + j;
                    float av = abuf[sr_bb][n];
                    uint4 u  = *(const uint4*)(rB + n * (2 * MP2));
                    float2 f0 = __half22float2(*(__half2*)&u.x);
                    float2 f1 = __half22float2(*(__half2*)&u.y);
                    float2 f2 = __half22float2(*(__half2*)&u.z);
                    float2 f3 = __half22float2(*(__half2*)&u.w);
                    a0 = fmaf(av, f0.x, a0); a1 = fmaf(av, f0.y, a1);
                    a2 = fmaf(av, f1.x, a2); a3 = fmaf(av, f1.y, a3);
                    a4 = fmaf(av, f2.x, a4); a5 = fmaf(av, f2.y, a5);
                    a6 = fmaf(av, f3.x, a6); a7 = fmaf(av, f3.y, a7);
                }
            }
#define RED(A) A += __shfl_xor(A, 4, 64); A += __shfl_xor(A, 8, 64); \
               A += __shfl_xor(A, 16, 64); A += __shfl_xor(A, 32, 64);
            RED(a0) RED(a1) RED(a2) RED(a3) RED(a4) RED(a5) RED(a6) RED(a7)
#undef RED
            if (lane < 4) {     // rg == 0 lanes hold full sums; rs == lane
                int m = sr_mq * 32 + lane * 8;
                float4 lo = {a0, a1, a2, a3}, hi = {a4, a5, a6, a7};
                *(float4*)&xcat2[sr_bb][m]     = lo;
                *(float4*)&xcat2[sr_bb][m + 4] = hi;
                uint4 hv;
                hv.x = PKRTZ(a0, a1);
                hv.y = PKRTZ(a2, a3);
                hv.z = PKRTZ(a4, a5);
                hv.w = PKRTZ(a6, a7);
                *(uint4*)&xcath[sr_bb][m] = hv;
            }
        }
        __syncthreads();
    }

    // ---- output: [q | read], 4 batches x 256 ----
    {
        int bb = tid >> 8, j = tid & 255;
        float v = (j < 128) ? xcat2[bb][128 + j] : xcat2[bb][j - 128];
        out[((long)(b0 + bb) << 8) + j] = v;
    }
}

extern "C" void kernel_launch(void* const* d_in, const int* in_sizes, int n_in,
                              void* d_out, int out_size, void* d_ws, size_t ws_size,
                              hipStream_t stream) {
    const float* hidden = (const float*)d_in[0];
    const float* input  = (const float*)d_in[1];
    const float* W_emb  = (const float*)d_in[2];
    const float* b_emb  = (const float*)d_in[3];
    const float* W_ih   = (const float*)d_in[4];
    const float* b_ih   = (const float*)d_in[5];
    const float* W_hh   = (const float*)d_in[6];
    const float* b_hh   = (const float*)d_in[7];
    const unsigned char* mask = (const unsigned char*)d_in[8];
    const int*  Tptr    = (const int*)d_in[9];
    float* ws   = (float*)d_ws;
    float* outp = (float*)d_out;

    hipLaunchKernelGGL(prep_kernel, dim3(128), dim3(256), 0, stream,
                       W_emb, W_ih, b_ih, W_hh, b_hh, ws);
    hipLaunchKernelGGL(set2vec_main, dim3(512), dim3(1024), 0, stream,
                       hidden, input, b_emb, mask, Tptr, ws, outp);
}

// Round 17
// 168.112 us; speedup vs baseline: 1.4069x; 1.0853x over previous
//
#include <hip/hip_runtime.h>
#include <hip/hip_fp16.h>
#include <math.h>

#define BIG_NEG  (-1.0e6f)
#define NN   100
#define MD   128
#define KD   256
#define G4   512
#define NB   4    // batch elements per block
#define MP2  68   // __half2 stride per mem row (272 B, 16B-aligned)

// ws layout:
//   halves [0, 32768)       : WembF embed B-frags [kg:32][m:128][j:8]
//   halves [32768, 163840)  : WGF gates B-frags [kc:32][g:512][j:8], k = kc*8+j
//   floats [81920, 82432)   : biasc = b_ih + b_hh
#define WS_WGF_H  32768
#define WS_BIAS_F 81920

typedef _Float16 f16x2 __attribute__((ext_vector_type(2)));
typedef _Float16 f16x8 __attribute__((ext_vector_type(8)));
typedef float    f32x4 __attribute__((ext_vector_type(4)));

#if __has_builtin(__builtin_amdgcn_rcpf)
#define RCPF(x) __builtin_amdgcn_rcpf(x)
#else
#define RCPF(x) (1.0f / (x))
#endif

#define PKRTZ(a, b) __builtin_bit_cast(unsigned, __builtin_amdgcn_cvt_pkrtz((a), (b)))

__device__ __forceinline__ float sigm(float x) {
    return RCPF(1.0f + __expf(-x));          // x<<0: exp=inf -> rcp=0, no NaN
}
__device__ __forceinline__ float tanh_f(float x) {
    float xc = fminf(fmaxf(x, -15.0f), 15.0f);
    float e  = __expf(2.0f * xc);
    return (e - 1.0f) * RCPF(e + 1.0f);
}

extern "C" __global__ void prep_kernel(const float* __restrict__ W_emb,
                                       const float* __restrict__ W_ih,
                                       const float* __restrict__ b_ih,
                                       const float* __restrict__ W_hh,
                                       const float* __restrict__ b_hh,
                                       float* __restrict__ ws) {
    int tid = blockIdx.x * blockDim.x + threadIdx.x;
    int nth = gridDim.x * blockDim.x;
    __half* WF    = (__half*)ws;
    __half* WG    = (__half*)ws + WS_WGF_H;
    float*  biasc = ws + WS_BIAS_F;
    for (int i = tid; i < 32768; i += nth) {
        int kg = i >> 10, m = (i >> 3) & 127, j = i & 7;
        WF[i] = __float2half(W_emb[m * 256 + kg * 8 + j]);
    }
    for (int i = tid; i < 131072; i += nth) {
        int kc = i >> 12, g = (i >> 3) & 511, j = i & 7;
        int k = kc * 8 + j;
        float w = (k < 128) ? W_ih[g * 128 + k] : W_hh[g * 128 + (k - 128)];
        WG[i] = __float2half(w);
    }
    for (int i = tid; i < 512; i += nth) biasc[i] = b_ih[i] + b_hh[i];
}

extern "C" __global__ __launch_bounds__(1024, 4)
void set2vec_main(const float* __restrict__ hidden,
                  const float* __restrict__ input,
                  const float* __restrict__ b_emb,
                  const unsigned char* __restrict__ mask_bytes,
                  const int* __restrict__ Tptr,
                  const float* __restrict__ ws,
                  float* __restrict__ out) {
    __shared__ __half2 mem2[NB][NN][MP2];    // 108800 B fp16 memory [bb][n][m-pair]
    __shared__ __half  xi[32][NB][8];        // interleaved fp16 [lstm_in|h]: xi[k>>3][b][k&7]
    __shared__ float   xcat2[NB][KD];        // fp32 [lstm_in | h]
    __shared__ float   cbuf[NB][MD];
    __shared__ float   emask[NB][NN];
    __shared__ float   bbuf[G4];
    __shared__ int     mask_is_u8;
    __shared__ float   gbuf[NB][G4];         // gates output
    __shared__ float   ebuf[NB][128];        // energies output (mask folded in)
    __shared__ float   abuf[NB][NN];         // attn weights

    const int tid  = threadIdx.x;
    const int b0   = blockIdx.x * NB;
    const int lane = tid & 63, wv = tid >> 6;
    const int ln15 = lane & 15, lhi = lane >> 4;
    const __half* WF   = (const __half*)ws;
    const __half* memh = (const __half*)mem2;
    const __half* xih  = (const __half*)xi;

    if (tid == 0) {
        int nz = 0;
        for (int i = 0; i < 64; ++i)
            if ((i & 3) && mask_bytes[i]) nz = 1;
        mask_is_u8 = nz;
    }

    // ---- fused embed via MFMA: mem = fp16(cat(hidden,input) @ W_emb^T + b_emb) ----
    {
        const float be0 = b_emb[0 * 16 + ln15], be1 = b_emb[1 * 16 + ln15];
        const float be2 = b_emb[2 * 16 + ln15], be3 = b_emb[3 * 16 + ln15];
        const float be4 = b_emb[4 * 16 + ln15], be5 = b_emb[5 * 16 + ln15];
        const float be6 = b_emb[6 * 16 + ln15], be7 = b_emb[7 * 16 + ln15];
        __half* memw = (__half*)mem2;
        for (int tile = wv; tile < 25; tile += 16) {   // 25 row-tiles of 16
            f32x4 acc0 = {be0, be0, be0, be0}, acc1 = {be1, be1, be1, be1};
            f32x4 acc2 = {be2, be2, be2, be2}, acc3 = {be3, be3, be3, be3};
            f32x4 acc4 = {be4, be4, be4, be4}, acc5 = {be5, be5, be5, be5};
            f32x4 acc6 = {be6, be6, be6, be6}, acc7 = {be7, be7, be7, be7};

            const int rA     = tile * 16 + ln15;
            const int rAok   = rA < NB * NN;
            const long gbase = ((long)(b0 * NN + rA)) << 7;

            #pragma unroll 1
            for (int mk = 0; mk < 8; ++mk) {
                f16x8 aF;
                if (rAok) {
                    int k0 = mk * 32 + lhi * 8;
                    const float* src = (k0 < 128) ? (hidden + gbase + k0)
                                                  : (input + gbase + (k0 - 128));
                    float4 v0 = *(const float4*)src;
                    float4 v1 = *(const float4*)(src + 4);
                    union { f16x8 v; unsigned u[4]; } au;
                    au.u[0] = PKRTZ(v0.x, v0.y);
                    au.u[1] = PKRTZ(v0.z, v0.w);
                    au.u[2] = PKRTZ(v1.x, v1.y);
                    au.u[3] = PKRTZ(v1.z, v1.w);
                    aF = au.v;
                } else {
                    aF = (f16x8)(_Float16)0.0f;
                }
                const __half* wrow = WF + ((mk * 4 + lhi) * 128 + ln15) * 8;
#define EMB_CT(CT, ACC) { \
                union { uint4 u; f16x8 v; } bu; \
                bu.u = *(const uint4*)(wrow + (CT * 16) * 8); \
                ACC = __builtin_amdgcn_mfma_f32_16x16x32_f16(aF, bu.v, ACC, 0, 0, 0); }
                EMB_CT(0, acc0) EMB_CT(1, acc1) EMB_CT(2, acc2) EMB_CT(3, acc3)
                EMB_CT(4, acc4) EMB_CT(5, acc5) EMB_CT(6, acc6) EMB_CT(7, acc7)
#undef EMB_CT
            }
#define EMB_WR(CT, ACC) { \
            _Pragma("unroll") \
            for (int reg = 0; reg < 4; ++reg) { \
                int r = tile * 16 + lhi * 4 + reg; \
                if (r < NB * NN) { \
                    int bb = r / NN, n = r - (r / NN) * NN; \
                    memw[(bb * NN + n) * (2 * MP2) + CT * 16 + ln15] = __float2half(ACC[reg]); \
                } } }
            EMB_WR(0, acc0) EMB_WR(1, acc1) EMB_WR(2, acc2) EMB_WR(3, acc3)
            EMB_WR(4, acc4) EMB_WR(5, acc5) EMB_WR(6, acc6) EMB_WR(7, acc7)
#undef EMB_WR
        }
    }

    // ---- gate weight pointers (streamed from L2 each step) ----
    const uint4* WgB = (const uint4*)((const __half*)ws + WS_WGF_H);
    const int ct0 = wv * 2, ct1 = wv * 2 + 1;

    // ---- init LSTM state + mask + bias tables ----
    if (tid < 1024) ((__half*)xi)[tid] = __float2half(0.0f);   // 32*4*8 = 1024
    ((float*)xcat2)[tid] = 0.0f;                               // NB*KD = 1024
    if (tid < NB * MD) ((float*)cbuf)[tid] = 0.0f;
    if (tid < G4) bbuf[tid] = ws[WS_BIAS_F + tid];
    if (tid < NB * NN) {
        int bb = tid / NN, n = tid - bb * NN;
        long mrow = (long)(b0 + bb) * NN + n;
        int valid = mask_is_u8 ? (mask_bytes[mrow] != 0)
                               : (((const int*)mask_bytes)[mrow] != 0);
        emask[bb][n] = valid ? 0.0f : BIG_NEG;
    }
    __syncthreads();

    const int T = Tptr[0];

    // ---- per-thread phase constants ----
    // gates A-read: xi[(KS*4+lhi)][ln15&3][0..7] -> 4-way same-address broadcast
    const __half* aBase = xih + (ln15 & 3) * 8 + lhi * 32;

    // energies: wave wv<14 handles pairs (bb,ntile) p=2wv, 2wv+1 of 28
    const int ep0 = wv * 2, ep1 = wv * 2 + 1;
    const int e_bb0 = ep0 / 7, e_nt0 = ep0 - e_bb0 * 7;
    const int e_bb1 = ep1 / 7, e_nt1 = ep1 - e_bb1 * 7;
    const int e_n0  = e_nt0 * 16 + ln15, e_n1 = e_nt1 * 16 + ln15;
    const int e_n0c = (e_n0 < 100) ? e_n0 : 99;        // clamp OOB lanes (result discarded)
    const int e_n1c = (e_n1 < 100) ? e_n1 : 99;
    const __half* eB0 = memh + (e_bb0 * NN + e_n0c) * (2 * MP2) + lhi * 8;
    const __half* eB1 = memh + (e_bb1 * NN + e_n1c) * (2 * MP2) + lhi * 8;
    // q (h) lives at k=128.. -> xi blocks 16..31
    const __half* eA0 = xih + 512 + lhi * 32 + e_bb0 * 8;
    const __half* eA1 = xih + 512 + lhi * 32 + e_bb1 * 8;

    // fused softmax+read: 8 waves, wave = (bb = wv>>1, mh = wv&1)
    // lane = rg*8 + rs: rg = n-group (5x13 + 3x12... 4x13,4x12), rs = m-slice of 8
    const int sr_bb = (wv >> 1) & 3, sr_mh = wv & 1;
    const int rg = lane >> 3, rs = lane & 7;
    const int r_start = (rg <= 4) ? rg * 13 : 64 + (rg - 5) * 12;
    const int r_cnt   = (rg < 4) ? 13 : 12;
    const __half* rB = memh + sr_bb * NN * (2 * MP2) + sr_mh * 64 + rs * 8;

    for (int step = 0; step < T; ++step) {
        // --- gates via MFMA: X[4,256] @ Wcat^T -> gbuf[4][512] ---
        {
            f32x4 ga = {0.f, 0.f, 0.f, 0.f}, gb = {0.f, 0.f, 0.f, 0.f};
#define GS(KS) { \
            union { uint4 u; f16x8 v; } a, ba, bc; \
            a.u  = *(const uint4*)(aBase + (KS) * 128); \
            ba.u = WgB[((KS) * 4 + lhi) * 512 + ct0 * 16 + ln15]; \
            bc.u = WgB[((KS) * 4 + lhi) * 512 + ct1 * 16 + ln15]; \
            ga = __builtin_amdgcn_mfma_f32_16x16x32_f16(a.v, ba.v, ga, 0, 0, 0); \
            gb = __builtin_amdgcn_mfma_f32_16x16x32_f16(a.v, bc.v, gb, 0, 0, 0); }
            GS(0) GS(1) GS(2) GS(3) GS(4) GS(5) GS(6) GS(7)
#undef GS
            if (lhi == 0) {   // D rows 0-3 = batches 0-3
                #pragma unroll
                for (int r = 0; r < 4; ++r) {
                    gbuf[r][ct0 * 16 + ln15] = ga[r];
                    gbuf[r][ct1 * 16 + ln15] = gb[r];
                }
            }
        }
        __syncthreads();
        // --- LSTM pointwise (i,f,g,o), fast transcendentals ---
        if (tid < NB * MD) {
            int bb = tid >> 7, m = tid & 127;
            float gi = gbuf[bb][m]       + bbuf[m];
            float gf = gbuf[bb][128 + m] + bbuf[128 + m];
            float gg = gbuf[bb][256 + m] + bbuf[256 + m];
            float go = gbuf[bb][384 + m] + bbuf[384 + m];
            float c  = cbuf[bb][m];
            c = sigm(gf) * c + sigm(gi) * tanh_f(gg);
            float qv = sigm(go) * tanh_f(c);
            cbuf[bb][m] = c;
            xcat2[bb][128 + m] = qv;
            xi[16 + (m >> 3)][bb][m & 7] = __float2half(qv);   // h at k=128+m
        }
        __syncthreads();
        // --- energies via per-batch MFMA (A-rows broadcast = q_bb); emask folded in ---
        if (wv < 14) {
            f32x4 e0 = {0.f, 0.f, 0.f, 0.f}, e1 = {0.f, 0.f, 0.f, 0.f};
#define ES(KS) { \
            union { uint4 u; f16x8 v; } a0, a1, bq0, bq1; \
            a0.u  = *(const uint4*)(eA0 + (KS) * 128); \
            bq0.u = *(const uint4*)(eB0 + (KS) * 32); \
            a1.u  = *(const uint4*)(eA1 + (KS) * 128); \
            bq1.u = *(const uint4*)(eB1 + (KS) * 32); \
            e0 = __builtin_amdgcn_mfma_f32_16x16x32_f16(a0.v, bq0.v, e0, 0, 0, 0); \
            e1 = __builtin_amdgcn_mfma_f32_16x16x32_f16(a1.v, bq1.v, e1, 0, 0, 0); }
            ES(0) ES(1) ES(2) ES(3)
#undef ES
            if (lhi == 0) {
                if (e_n0 < 100) ebuf[e_bb0][e_n0] = e0[0] + emask[e_bb0][e_n0];
                if (e_n1 < 100) ebuf[e_bb1][e_n1] = e1[0] + emask[e_bb1][e_n1];
            }
        }
        __syncthreads();
        // --- fused softmax+read: 8 waves (2 per bb, redundant softmax) ---
        if (wv < 8) {
            // softmax in-wave (benign same-value race on abuf between the 2 waves per bb)
            {
                float e0 = ebuf[sr_bb][lane];
                float e1 = (lane < 36) ? ebuf[sr_bb][64 + lane] : -INFINITY;
                float mx = fmaxf(e0, e1);
                for (int off = 32; off; off >>= 1) mx = fmaxf(mx, __shfl_xor(mx, off, 64));
                float p0 = __expf(e0 - mx);
                float p1 = (lane < 36) ? __expf(e1 - mx) : 0.0f;
                float s = p0 + p1;
                for (int off = 32; off; off >>= 1) s += __shfl_xor(s, off, 64);
                float inv = RCPF(s);
                abuf[sr_bb][lane] = p0 * inv;
                if (lane < 36) abuf[sr_bb][64 + lane] = p1 * inv;
            }
            // read: each lane accumulates its n-group over its m-slice
            float a0 = 0.f, a1 = 0.f, a2 = 0.f, a3 = 0.f;
            float a4 = 0.f, a5 = 0.f, a6 = 0.f, a7 = 0.f;
            #pragma unroll
            for (int j = 0; j < 13; ++j) {
                if (j < r_cnt) {
                    int n = r_start + j;
                    float av = abuf[sr_bb][n];
                    uint4 u  = *(const uint4*)(rB + n * (2 * MP2));
                    float2 f0 = __half22float2(*(__half2*)&u.x);
                    float2 f1 = __half22float2(*(__half2*)&u.y);
                    float2 f2 = __half22float2(*(__half2*)&u.z);
                    float2 f3 = __half22float2(*(__half2*)&u.w);
                    a0 = fmaf(av, f0.x, a0); a1 = fmaf(av, f0.y, a1);
                    a2 = fmaf(av, f1.x, a2); a3 = fmaf(av, f1.y, a3);
                    a4 = fmaf(av, f2.x, a4); a5 = fmaf(av, f2.y, a5);
                    a6 = fmaf(av, f3.x, a6); a7 = fmaf(av, f3.y, a7);
                }
            }
#define RED(A) A += __shfl_xor(A, 8, 64); A += __shfl_xor(A, 16, 64); A += __shfl_xor(A, 32, 64);
            RED(a0) RED(a1) RED(a2) RED(a3) RED(a4) RED(a5) RED(a6) RED(a7)
#undef RED
            if (lane < 8) {     // rg == 0 lanes hold full sums; rs == lane
                int m = sr_mh * 64 + lane * 8;
                float4 lo = {a0, a1, a2, a3}, hi = {a4, a5, a6, a7};
                *(float4*)&xcat2[sr_bb][m]     = lo;
                *(float4*)&xcat2[sr_bb][m + 4] = hi;
                uint4 hv;
                hv.x = PKRTZ(a0, a1);
                hv.y = PKRTZ(a2, a3);
                hv.z = PKRTZ(a4, a5);
                hv.w = PKRTZ(a6, a7);
                *(uint4*)&xi[m >> 3][sr_bb][0] = hv;   // lstm_in at k=m
            }
        }
        __syncthreads();
    }

    // ---- output: [q | read], 4 batches x 256 ----
    {
        int bb = tid >> 8, j = tid & 255;
        float v = (j < 128) ? xcat2[bb][128 + j] : xcat2[bb][j - 128];
        out[((long)(b0 + bb) << 8) + j] = v;
    }
}

extern "C" void kernel_launch(void* const* d_in, const int* in_sizes, int n_in,
                              void* d_out, int out_size, void* d_ws, size_t ws_size,
                              hipStream_t stream) {
    const float* hidden = (const float*)d_in[0];
    const float* input  = (const float*)d_in[1];
    const float* W_emb  = (const float*)d_in[2];
    const float* b_emb  = (const float*)d_in[3];
    const float* W_ih   = (const float*)d_in[4];
    const float* b_ih   = (const float*)d_in[5];
    const float* W_hh   = (const float*)d_in[6];
    const float* b_hh   = (const float*)d_in[7];
    const unsigned char* mask = (const unsigned char*)d_in[8];
    const int*  Tptr    = (const int*)d_in[9];
    float* ws   = (float*)d_ws;
    float* outp = (float*)d_out;

    hipLaunchKernelGGL(prep_kernel, dim3(128), dim3(256), 0, stream,
                       W_emb, W_ih, b_ih, W_hh, b_hh, ws);
    hipLaunchKernelGGL(set2vec_main, dim3(512), dim3(1024), 0, stream,
                       hidden, input, b_emb, mask, Tptr, ws, outp);
}